// Round 8
// baseline (5322.520 us; speedup 1.0000x reference)
//
#include <hip/hip_runtime.h>

#define NN 100000
#define NE 600000
#define NP 100096   // 391*256, padded node count
#define NB 391
#define WSTR 2308   // w1bs per-ks stride: 64*36+4 (skewed banks)

typedef float v4    __attribute__((ext_vector_type(4)));
typedef float f32x4 __attribute__((ext_vector_type(4)));
typedef short s16x4 __attribute__((ext_vector_type(4)));
typedef short s16x8 __attribute__((ext_vector_type(8)));

__device__ __forceinline__ short f2bf(float f) {
    unsigned u = __float_as_uint(f);
    u = (u + 0x7fffu + ((u >> 16) & 1u)) >> 16;
    return (short)u;
}

// ---------------------------------------------------------------------------
// CSR construction: histogram -> scan -> fill
// ---------------------------------------------------------------------------
__global__ __launch_bounds__(256) void hist_kernel(const int* __restrict__ ei,
                                                   int* __restrict__ deg) {
    int e = blockIdx.x * 256 + threadIdx.x;
    if (e < NE) atomicAdd(&deg[ei[e]], 1);
}

__global__ __launch_bounds__(256) void scan1_kernel(const int* __restrict__ deg,
                                                    int* __restrict__ partial,
                                                    int* __restrict__ bsum) {
    __shared__ int tmp[256];
    int t = threadIdx.x;
    int i = blockIdx.x * 256 + t;
    int v = deg[i];
    tmp[t] = v;
    __syncthreads();
    for (int off = 1; off < 256; off <<= 1) {
        int add = (t >= off) ? tmp[t - off] : 0;
        __syncthreads();
        tmp[t] += add;
        __syncthreads();
    }
    partial[i] = tmp[t] - v;
    if (t == 255) bsum[blockIdx.x] = tmp[255];
}

__global__ __launch_bounds__(512) void scan2_kernel(const int* __restrict__ bsum,
                                                    int* __restrict__ boff) {
    __shared__ int tmp[512];
    int t = threadIdx.x;
    int v = (t < NB) ? bsum[t] : 0;
    tmp[t] = v;
    __syncthreads();
    for (int off = 1; off < 512; off <<= 1) {
        int add = (t >= off) ? tmp[t - off] : 0;
        __syncthreads();
        tmp[t] += add;
        __syncthreads();
    }
    boff[t] = tmp[t] - v;
}

__global__ __launch_bounds__(256) void scan3_kernel(const int* __restrict__ partial,
                                                    const int* __restrict__ boff,
                                                    int* __restrict__ base,
                                                    int* __restrict__ cursor) {
    int i = blockIdx.x * 256 + threadIdx.x;
    int b = partial[i] + boff[blockIdx.x];
    base[i] = b;
    cursor[i] = b;
}

__global__ __launch_bounds__(256) void fill_kernel(const int* __restrict__ ei,
                                                   int* __restrict__ cursor,
                                                   int* __restrict__ csr) {
    int e = blockIdx.x * 256 + threadIdx.x;
    if (e < NE) {
        int r = ei[e];
        int p = atomicAdd(&cursor[r], 1);
        csr[p] = e;
    }
}

// ---------------------------------------------------------------------------
// Degree counting sort: nodes grouped by degree so waves are balanced.
// ---------------------------------------------------------------------------
__global__ __launch_bounds__(256) void dhist_kernel(const int* __restrict__ deg,
                                                    int* __restrict__ dhist) {
    int i = blockIdx.x * 256 + threadIdx.x;
    if (i < NN) atomicAdd(&dhist[min(deg[i], 63)], 1);
}

__global__ __launch_bounds__(64) void dscan_kernel(const int* __restrict__ dhist,
                                                   int* __restrict__ dcur) {
    __shared__ int tmp[64];
    int t = threadIdx.x;
    int v = dhist[t];
    tmp[t] = v;
    __syncthreads();
    for (int off = 1; off < 64; off <<= 1) {
        int add = (t >= off) ? tmp[t - off] : 0;
        __syncthreads();
        tmp[t] += add;
        __syncthreads();
    }
    dcur[t] = tmp[t] - v;
}

__global__ __launch_bounds__(256) void dscatter_kernel(const int* __restrict__ deg,
                                                       int* __restrict__ dcur,
                                                       int* __restrict__ node_order) {
    int i = blockIdx.x * 256 + threadIdx.x;
    if (i < NN) {
        int b = min(deg[i], 63);
        int p = atomicAdd(&dcur[b], 1);
        node_order[p] = i;
    }
}

// ---------------------------------------------------------------------------
// Weight prep: W2aT [256][160] bf16 with z-reorder [agg(128), x(2), u(2), 0*28]
//              W2bT [512][256] bf16   (both B^T layout: [N][K], K contiguous)
// ---------------------------------------------------------------------------
__global__ __launch_bounds__(256) void prep_kernel(const float* __restrict__ W2a,
                                                   const float* __restrict__ W2b,
                                                   short* __restrict__ W2aT,
                                                   short* __restrict__ W2bT) {
    int idx = blockIdx.x * 256 + threadIdx.x;
    if (idx < 256 * 160) {
        int n = idx / 160, k = idx - n * 160;
        float v = 0.f;
        if (k < 128)       v = W2a[(2 + k) * 256 + n];
        else if (k == 128) v = W2a[0 * 256 + n];
        else if (k == 129) v = W2a[1 * 256 + n];
        else if (k == 130) v = W2a[130 * 256 + n];
        else if (k == 131) v = W2a[131 * 256 + n];
        W2aT[idx] = f2bf(v);
    }
    if (idx < 512 * 256) {
        int n = idx >> 8, k = idx & 255;
        W2bT[idx] = f2bf(W2b[k * 512 + n]);
    }
}

// ---------------------------------------------------------------------------
// agg2: 4 threads per node (k-split of 128 cols into 4x32), degree-sorted
// node order, 4-edge presum. Accumulators are EIGHT NAMED v4 SSA VALUES —
// R6/R7's float acc[32] was scratch-allocated (9-10 GB/dispatch RMW traffic,
// VALUBusy <2%). Named vectors cannot be scratch-indexed -> guaranteed VGPR.
// ---------------------------------------------------------------------------
__global__ __launch_bounds__(256, 2) void agg2_kernel(
    const float* __restrict__ x, const int* __restrict__ ei,
    const float* __restrict__ ea,
    const float* __restrict__ W1a, const float* __restrict__ b1a,
    const float* __restrict__ W1b, const float* __restrict__ b1b,
    const int* __restrict__ base, const int* __restrict__ deg,
    const int* __restrict__ csr, const int* __restrict__ node_order,
    float* __restrict__ agg)
{
    __shared__ float w1a[256];
    __shared__ float ba[64];
    __shared__ float bbs[128];
    __shared__ float w1bs[4 * WSTR];   // [ks][k*36 + c], skewed per ks
    const int tid = threadIdx.x;

    w1a[tid] = W1a[tid];
    if (tid < 64)  ba[tid] = b1a[tid];
    if (tid < 128) bbs[tid] = b1b[tid];
    for (int idx = tid; idx < 8192; idx += 256) {
        int k = idx >> 7, c = idx & 127;
        w1bs[(c >> 5) * WSTR + k * 36 + (c & 31)] = W1b[idx];
    }
    __syncthreads();

    const int g  = blockIdx.x * 256 + tid;
    const int ni = g >> 2, ks = g & 3;
    const bool act = ni < NN;
    const int n  = act ? node_order[ni] : 0;
    const int d  = act ? deg[n] : 0;
    const int b0 = act ? base[n] : 0;
    const float* wslice = &w1bs[ks * WSTR];

    v4 acc0 = {0.f,0.f,0.f,0.f}, acc1 = {0.f,0.f,0.f,0.f};
    v4 acc2 = {0.f,0.f,0.f,0.f}, acc3 = {0.f,0.f,0.f,0.f};
    v4 acc4 = {0.f,0.f,0.f,0.f}, acc5 = {0.f,0.f,0.f,0.f};
    v4 acc6 = {0.f,0.f,0.f,0.f}, acc7 = {0.f,0.f,0.f,0.f};

    for (int i = 0; i < d; i += 4) {
        int eA = csr[b0 + i];
        bool vB = (i + 1) < d, vC = (i + 2) < d, vD = (i + 3) < d;
        int eB = vB ? csr[b0 + i + 1] : eA;
        int eC = vC ? csr[b0 + i + 2] : eA;
        int eD = vD ? csr[b0 + i + 3] : eA;
        int cA = ei[NE + eA], cB = ei[NE + eB];
        int cC = ei[NE + eC], cD = ei[NE + eD];
        float a0 = x[2 * cA], a1 = x[2 * cA + 1], a2 = ea[2 * eA], a3 = ea[2 * eA + 1];
        float b0f = x[2 * cB], b1f = x[2 * cB + 1], b2f = ea[2 * eB], b3f = ea[2 * eB + 1];
        float c0 = x[2 * cC], c1 = x[2 * cC + 1], c2 = ea[2 * eC], c3 = ea[2 * eC + 1];
        float d0 = x[2 * cD], d1 = x[2 * cD + 1], d2 = ea[2 * eD], d3 = ea[2 * eD + 1];

#pragma unroll
        for (int kg = 0; kg < 16; ++kg) {
            v4 r0 = *(const v4*)&w1a[kg * 4];
            v4 r1 = *(const v4*)&w1a[64 + kg * 4];
            v4 r2 = *(const v4*)&w1a[128 + kg * 4];
            v4 r3 = *(const v4*)&w1a[192 + kg * 4];
            v4 bb4 = *(const v4*)&ba[kg * 4];

#define HM(M) ({ float va_ = bb4[M] + a0*r0[M] + a1*r1[M] + a2*r2[M] + a3*r3[M];   \
                 float vb_ = bb4[M] + b0f*r0[M] + b1f*r1[M] + b2f*r2[M] + b3f*r3[M];\
                 float vc_ = bb4[M] + c0*r0[M] + c1*r1[M] + c2*r2[M] + c3*r3[M];   \
                 float vd_ = bb4[M] + d0*r0[M] + d1*r1[M] + d2*r2[M] + d3*r3[M];   \
                 fmaxf(va_, 0.f) + (vB ? fmaxf(vb_, 0.f) : 0.f)                    \
                                 + (vC ? fmaxf(vc_, 0.f) : 0.f)                    \
                                 + (vD ? fmaxf(vd_, 0.f) : 0.f); })
            float h0 = HM(0);
            float h1 = HM(1);
            float h2 = HM(2);
            float h3 = HM(3);
#undef HM

#define WROW(HH, M) { const float* wr_ = &wslice[(kg * 4 + (M)) * 36];             \
                      acc0 += (HH) * *(const v4*)&wr_[0];                          \
                      acc1 += (HH) * *(const v4*)&wr_[4];                          \
                      acc2 += (HH) * *(const v4*)&wr_[8];                          \
                      acc3 += (HH) * *(const v4*)&wr_[12];                         \
                      acc4 += (HH) * *(const v4*)&wr_[16];                         \
                      acc5 += (HH) * *(const v4*)&wr_[20];                         \
                      acc6 += (HH) * *(const v4*)&wr_[24];                         \
                      acc7 += (HH) * *(const v4*)&wr_[28]; }
            WROW(h0, 0)
            WROW(h1, 1)
            WROW(h2, 2)
            WROW(h3, 3)
#undef WROW
        }
    }

    if (act) {
        float inv = (d > 0) ? 1.0f / (float)d : 0.f;
        float* dst = &agg[(size_t)n * 128 + ks * 32];
        const float* bp = &bbs[ks * 32];
        bool nz = d > 0;
        auto store = [&](v4 a, int j) {
            v4 o;
            o[0] = nz ? (a[0] * inv + bp[j * 4 + 0]) : 0.f;
            o[1] = nz ? (a[1] * inv + bp[j * 4 + 1]) : 0.f;
            o[2] = nz ? (a[2] * inv + bp[j * 4 + 2]) : 0.f;
            o[3] = nz ? (a[3] * inv + bp[j * 4 + 3]) : 0.f;
            *(v4*)&dst[j * 4] = o;
        };
        store(acc0, 0); store(acc1, 1); store(acc2, 2); store(acc3, 3);
        store(acc4, 4); store(acc5, 5); store(acc6, 6); store(acc7, 7);
    }
}

// ---------------------------------------------------------------------------
// Node MFMA kernel (unchanged): 64 nodes/block, 8 waves, bf16 MFMA.
// ---------------------------------------------------------------------------
__global__ __launch_bounds__(512, 2) void node_mfma_kernel(
    const float* __restrict__ x, const float* __restrict__ u,
    const int* __restrict__ batch,
    const float* __restrict__ agg,
    const short* __restrict__ W2aT, const short* __restrict__ W2bT,
    const float* __restrict__ b2a, const float* __restrict__ b2b,
    float* __restrict__ out)
{
    __shared__ short zb[64 * 192];
    __shared__ short tb[64 * 256];
    const int tid = threadIdx.x;
    const int node0 = blockIdx.x * 64;

#pragma unroll
    for (int it = 0; it < 4; ++it) {
        int idx = it * 512 + tid;
        int r = idx >> 5, c = idx & 31;
        int node = node0 + r;
        f32x4 v = {0.f, 0.f, 0.f, 0.f};
        if (node < NN) v = *(const f32x4*)&agg[(size_t)node * 128 + c * 4];
        s16x4 p;
        p[0] = f2bf(v[0]); p[1] = f2bf(v[1]); p[2] = f2bf(v[2]); p[3] = f2bf(v[3]);
        int ch = c >> 1;
        int sw = (ch & ~7) | ((ch ^ r) & 7);
        *(s16x4*)&zb[r * 192 + sw * 8 + (c & 1) * 4] = p;
    }
    if (tid < 64) {
        int r = tid, node = node0 + r;
        s16x8 p = {0, 0, 0, 0, 0, 0, 0, 0};
        if (node < NN) {
            p[0] = f2bf(x[node * 2]); p[1] = f2bf(x[node * 2 + 1]);
            int b = batch[node];
            p[2] = f2bf(u[b * 2]); p[3] = f2bf(u[b * 2 + 1]);
        }
        int sw = 16 | (r & 7);
        *(s16x8*)&zb[r * 192 + sw * 8] = p;
    } else if (tid < 256) {
        int t2 = tid - 64;
        int r = t2 & 63;
        int ch = 17 + (t2 >> 6);
        int sw = (ch & ~7) | ((ch ^ r) & 7);
        s16x8 zz = {0, 0, 0, 0, 0, 0, 0, 0};
        *(s16x8*)&zb[r * 192 + sw * 8] = zz;
    }
    __syncthreads();

    const int lane = tid & 63, wid = tid >> 6;
    const int l15 = lane & 15, lk = lane >> 4;
    const int nw = wid;

    f32x4 acc1[4][2];
#pragma unroll
    for (int mf = 0; mf < 4; ++mf)
#pragma unroll
        for (int nf = 0; nf < 2; ++nf)
            acc1[mf][nf] = (f32x4){0.f, 0.f, 0.f, 0.f};

#pragma unroll
    for (int ks = 0; ks < 5; ++ks) {
        s16x8 a[4], b[2];
        int cb = ks * 4 + lk;
#pragma unroll
        for (int mf = 0; mf < 4; ++mf) {
            int r = mf * 16 + l15;
            int sw = (cb & ~7) | ((cb ^ r) & 7);
            a[mf] = *(const s16x8*)&zb[r * 192 + sw * 8];
        }
#pragma unroll
        for (int nf = 0; nf < 2; ++nf) {
            int n = nw * 32 + nf * 16 + l15;
            b[nf] = *(const s16x8*)&W2aT[n * 160 + ks * 32 + lk * 8];
        }
#pragma unroll
        for (int mf = 0; mf < 4; ++mf)
#pragma unroll
            for (int nf = 0; nf < 2; ++nf)
                acc1[mf][nf] = __builtin_amdgcn_mfma_f32_16x16x32_bf16(
                    a[mf], b[nf], acc1[mf][nf], 0, 0, 0);
    }

#pragma unroll
    for (int nf = 0; nf < 2; ++nf) {
        int n = nw * 32 + nf * 16 + l15;
        float bias = b2a[n];
        int ch = n >> 3, off = n & 7;
#pragma unroll
        for (int mf = 0; mf < 4; ++mf) {
#pragma unroll
            for (int j = 0; j < 4; ++j) {
                int r = mf * 16 + lk * 4 + j;
                float vv = fmaxf(acc1[mf][nf][j] + bias, 0.f);
                int sw = (ch & ~7) | ((ch ^ r) & 7);
                tb[r * 256 + sw * 8 + off] = f2bf(vv);
            }
        }
    }
    __syncthreads();

    f32x4 acc2[4][4];
#pragma unroll
    for (int mf = 0; mf < 4; ++mf)
#pragma unroll
        for (int nf = 0; nf < 4; ++nf)
            acc2[mf][nf] = (f32x4){0.f, 0.f, 0.f, 0.f};

#pragma unroll
    for (int ks = 0; ks < 8; ++ks) {
        s16x8 a[4], b[4];
        int cb = ks * 4 + lk;
#pragma unroll
        for (int mf = 0; mf < 4; ++mf) {
            int r = mf * 16 + l15;
            int sw = (cb & ~7) | ((cb ^ r) & 7);
            a[mf] = *(const s16x8*)&tb[r * 256 + sw * 8];
        }
#pragma unroll
        for (int nf = 0; nf < 4; ++nf) {
            int n = nw * 64 + nf * 16 + l15;
            b[nf] = *(const s16x8*)&W2bT[n * 256 + ks * 32 + lk * 8];
        }
#pragma unroll
        for (int mf = 0; mf < 4; ++mf)
#pragma unroll
            for (int nf = 0; nf < 4; ++nf)
                acc2[mf][nf] = __builtin_amdgcn_mfma_f32_16x16x32_bf16(
                    a[mf], b[nf], acc2[mf][nf], 0, 0, 0);
    }

#pragma unroll
    for (int nf = 0; nf < 4; ++nf) {
        int n = nw * 64 + nf * 16 + l15;
        float bias = b2b[n];
#pragma unroll
        for (int mf = 0; mf < 4; ++mf) {
#pragma unroll
            for (int j = 0; j < 4; ++j) {
                int r = mf * 16 + lk * 4 + j;
                int node = node0 + r;
                if (node < NN)
                    out[(size_t)node * 512 + n] = acc2[mf][nf][j] + bias;
            }
        }
    }
}

extern "C" void kernel_launch(void* const* d_in, const int* in_sizes, int n_in,
                              void* d_out, int out_size, void* d_ws, size_t ws_size,
                              hipStream_t stream) {
    const float* x          = (const float*)d_in[0];
    const int*   edge_index = (const int*)d_in[1];
    const float* edge_attr  = (const float*)d_in[2];
    const float* u          = (const float*)d_in[3];
    const int*   batch      = (const int*)d_in[4];
    const float* W1a        = (const float*)d_in[5];
    const float* b1a        = (const float*)d_in[6];
    const float* W1b        = (const float*)d_in[7];
    const float* b1b        = (const float*)d_in[8];
    const float* W2a        = (const float*)d_in[9];
    const float* b2a        = (const float*)d_in[10];
    const float* W2b        = (const float*)d_in[11];
    const float* b2b        = (const float*)d_in[12];
    float* out = (float*)d_out;

    // workspace layout
    float* agg    = (float*)d_ws;                        // [NN,128] fp32
    short* W2aT   = (short*)(agg + (size_t)NN * 128);    // [256,160] bf16
    short* W2bT   = W2aT + 256 * 160;                    // [512,256] bf16
    int*   deg    = (int*)(W2bT + 512 * 256);            // [NP]
    int*   dhist  = deg + NP;                            // [64] (memset with deg)
    int*   partial= dhist + 64;                          // [NP]
    int*   bsum   = partial + NP;                        // [512]
    int*   boff   = bsum + 512;                          // [512]
    int*   base   = boff + 512;                          // [NP]
    int*   cursor = base + NP;                           // [NP]
    int*   csr    = cursor + NP;                         // [NE]
    int*   norder = csr + NE;                            // [NP]
    int*   dcur   = norder + NP;                         // [64]

    hipMemsetAsync(deg, 0, (NP + 64) * sizeof(int), stream);

    prep_kernel <<<512, 256, 0, stream>>>(W2a, W2b, W2aT, W2bT);
    hist_kernel <<<(NE + 255) / 256, 256, 0, stream>>>(edge_index, deg);
    scan1_kernel<<<NB, 256, 0, stream>>>(deg, partial, bsum);
    scan2_kernel<<<1, 512, 0, stream>>>(bsum, boff);
    scan3_kernel<<<NB, 256, 0, stream>>>(partial, boff, base, cursor);
    fill_kernel <<<(NE + 255) / 256, 256, 0, stream>>>(edge_index, cursor, csr);

    dhist_kernel   <<<NB, 256, 0, stream>>>(deg, dhist);
    dscan_kernel   <<<1, 64, 0, stream>>>(dhist, dcur);
    dscatter_kernel<<<NB, 256, 0, stream>>>(deg, dcur, norder);

    agg2_kernel<<<(NN * 4 + 255) / 256, 256, 0, stream>>>(
        x, edge_index, edge_attr, W1a, b1a, W1b, b1b, base, deg, csr, norder, agg);

    node_mfma_kernel<<<(NN + 63) / 64, 512, 0, stream>>>(
        x, u, batch, agg, W2aT, W2bT, b2a, b2b, out);
}

// Round 9
// 323.604 us; speedup vs baseline: 16.4476x; 16.4476x over previous
//
#include <hip/hip_runtime.h>

#define NN 100000
#define NE 600000
#define NP 100096   // 391*256, padded node count
#define NB 391

typedef float v4    __attribute__((ext_vector_type(4)));
typedef float f32x4 __attribute__((ext_vector_type(4)));
typedef short s16x4 __attribute__((ext_vector_type(4)));
typedef short s16x8 __attribute__((ext_vector_type(8)));

__device__ __forceinline__ short f2bf(float f) {
    unsigned u = __float_as_uint(f);
    u = (u + 0x7fffu + ((u >> 16) & 1u)) >> 16;
    return (short)u;
}
__device__ __forceinline__ float bf2f(unsigned short v) {
    return __uint_as_float(((unsigned)v) << 16);
}

// ---------------------------------------------------------------------------
// CSR construction: histogram -> scan -> fill (+cidx: col per CSR slot)
// ---------------------------------------------------------------------------
__global__ __launch_bounds__(256) void hist_kernel(const int* __restrict__ ei,
                                                   int* __restrict__ deg) {
    int e = blockIdx.x * 256 + threadIdx.x;
    if (e < NE) atomicAdd(&deg[ei[e]], 1);
}

__global__ __launch_bounds__(256) void scan1_kernel(const int* __restrict__ deg,
                                                    int* __restrict__ partial,
                                                    int* __restrict__ bsum) {
    __shared__ int tmp[256];
    int t = threadIdx.x;
    int i = blockIdx.x * 256 + t;
    int v = deg[i];
    tmp[t] = v;
    __syncthreads();
    for (int off = 1; off < 256; off <<= 1) {
        int add = (t >= off) ? tmp[t - off] : 0;
        __syncthreads();
        tmp[t] += add;
        __syncthreads();
    }
    partial[i] = tmp[t] - v;
    if (t == 255) bsum[blockIdx.x] = tmp[255];
}

__global__ __launch_bounds__(512) void scan2_kernel(const int* __restrict__ bsum,
                                                    int* __restrict__ boff) {
    __shared__ int tmp[512];
    int t = threadIdx.x;
    int v = (t < NB) ? bsum[t] : 0;
    tmp[t] = v;
    __syncthreads();
    for (int off = 1; off < 512; off <<= 1) {
        int add = (t >= off) ? tmp[t - off] : 0;
        __syncthreads();
        tmp[t] += add;
        __syncthreads();
    }
    boff[t] = tmp[t] - v;
}

__global__ __launch_bounds__(256) void scan3_kernel(const int* __restrict__ partial,
                                                    const int* __restrict__ boff,
                                                    int* __restrict__ base,
                                                    int* __restrict__ cursor) {
    int i = blockIdx.x * 256 + threadIdx.x;
    int b = partial[i] + boff[blockIdx.x];
    base[i] = b;
    cursor[i] = b;
}

__global__ __launch_bounds__(256) void fill_kernel(const int* __restrict__ ei,
                                                   int* __restrict__ cursor,
                                                   int* __restrict__ csr,
                                                   int* __restrict__ cidx) {
    int e = blockIdx.x * 256 + threadIdx.x;
    if (e < NE) {
        int r = ei[e];
        int p = atomicAdd(&cursor[r], 1);
        csr[p] = e;
        cidx[p] = ei[NE + e];
    }
}

// ---------------------------------------------------------------------------
// Weight prep (bf16, B^T layouts, K contiguous):
//  W2aT [256][160] with z-reorder [agg(128), x(2), u(2), 0*28]
//  W2bT [512][256]
//  W1aT [64][32]  (K=4 padded to 32 with zeros)
//  W1bT [128][64]
// ---------------------------------------------------------------------------
__global__ __launch_bounds__(256) void prep_kernel(const float* __restrict__ W2a,
                                                   const float* __restrict__ W2b,
                                                   const float* __restrict__ W1a,
                                                   const float* __restrict__ W1b,
                                                   short* __restrict__ W2aT,
                                                   short* __restrict__ W2bT,
                                                   short* __restrict__ W1aT,
                                                   short* __restrict__ W1bT) {
    int idx = blockIdx.x * 256 + threadIdx.x;
    if (idx < 256 * 160) {
        int n = idx / 160, k = idx - n * 160;
        float v = 0.f;
        if (k < 128)       v = W2a[(2 + k) * 256 + n];
        else if (k == 128) v = W2a[0 * 256 + n];
        else if (k == 129) v = W2a[1 * 256 + n];
        else if (k == 130) v = W2a[130 * 256 + n];
        else if (k == 131) v = W2a[131 * 256 + n];
        W2aT[idx] = f2bf(v);
    }
    if (idx < 512 * 256) {
        int n = idx >> 8, k = idx & 255;
        W2bT[idx] = f2bf(W2b[k * 512 + n]);
    }
    if (idx < 64 * 32) {
        int n = idx >> 5, k = idx & 31;
        W1aT[idx] = (k < 4) ? f2bf(W1a[k * 64 + n]) : (short)0;
    }
    if (idx < 128 * 64) {
        int n = idx >> 6, k = idx & 63;
        W1bT[idx] = f2bf(W1b[k * 128 + n]);
    }
}

// ---------------------------------------------------------------------------
// Edge MFMA kernel: 64 CSR-ordered edges/block, 256 threads (4 waves).
// in[64][32] bf16 (pad-stride 40), L1: K=32 (1 kstep) -> relu -> t1[64][64]
// (stride 72), L2: K=64 (2 ksteps) -> +b1b -> h[64][128] LDS (stride 136)
// -> coalesced bf16 write to h_csr[p][128].
// ---------------------------------------------------------------------------
__global__ __launch_bounds__(256) void edge_mfma_kernel(
    const float* __restrict__ x, const float* __restrict__ ea,
    const int* __restrict__ csr, const int* __restrict__ cidx,
    const short* __restrict__ W1aT, const short* __restrict__ W1bT,
    const float* __restrict__ b1a, const float* __restrict__ b1b,
    short* __restrict__ h_csr)
{
    __shared__ short in[64 * 40];
    __shared__ short t1[64 * 72];
    __shared__ short hb[64 * 136];
    const int tid = threadIdx.x;
    const int p0 = blockIdx.x * 64;

    // ---- stage input tile
    {
        int r = tid >> 2, q = tid & 3;
        s16x8 v = {0, 0, 0, 0, 0, 0, 0, 0};
        if (q == 0) {
            int p = p0 + r;
            int e = csr[p];
            int c = cidx[p];
            v[0] = f2bf(x[2 * c]);  v[1] = f2bf(x[2 * c + 1]);
            v[2] = f2bf(ea[2 * e]); v[3] = f2bf(ea[2 * e + 1]);
        }
        *(s16x8*)&in[r * 40 + q * 8] = v;
    }
    __syncthreads();

    const int lane = tid & 63, nw = tid >> 6;
    const int l15 = lane & 15, lk = lane >> 4;

    // ---- layer 1: K=32, wave nw covers cols nw*16..+16 (1 nfrag x 4 mfrag)
    f32x4 acc1_0 = {0.f,0.f,0.f,0.f}, acc1_1 = {0.f,0.f,0.f,0.f};
    f32x4 acc1_2 = {0.f,0.f,0.f,0.f}, acc1_3 = {0.f,0.f,0.f,0.f};
    {
        int n = nw * 16 + l15;
        s16x8 b = *(const s16x8*)&W1aT[n * 32 + lk * 8];
        s16x8 a0 = *(const s16x8*)&in[(0 * 16 + l15) * 40 + lk * 8];
        s16x8 a1 = *(const s16x8*)&in[(1 * 16 + l15) * 40 + lk * 8];
        s16x8 a2 = *(const s16x8*)&in[(2 * 16 + l15) * 40 + lk * 8];
        s16x8 a3 = *(const s16x8*)&in[(3 * 16 + l15) * 40 + lk * 8];
        acc1_0 = __builtin_amdgcn_mfma_f32_16x16x32_bf16(a0, b, acc1_0, 0, 0, 0);
        acc1_1 = __builtin_amdgcn_mfma_f32_16x16x32_bf16(a1, b, acc1_1, 0, 0, 0);
        acc1_2 = __builtin_amdgcn_mfma_f32_16x16x32_bf16(a2, b, acc1_2, 0, 0, 0);
        acc1_3 = __builtin_amdgcn_mfma_f32_16x16x32_bf16(a3, b, acc1_3, 0, 0, 0);
    }
    // ---- epilogue 1: relu(acc + b1a) -> t1.  D: col=l15, row=lk*4+j
    {
        int n = nw * 16 + l15;
        float bias = b1a[n];
#pragma unroll
        for (int j = 0; j < 4; ++j) {
            t1[(0 * 16 + lk * 4 + j) * 72 + n] = f2bf(fmaxf(acc1_0[j] + bias, 0.f));
            t1[(1 * 16 + lk * 4 + j) * 72 + n] = f2bf(fmaxf(acc1_1[j] + bias, 0.f));
            t1[(2 * 16 + lk * 4 + j) * 72 + n] = f2bf(fmaxf(acc1_2[j] + bias, 0.f));
            t1[(3 * 16 + lk * 4 + j) * 72 + n] = f2bf(fmaxf(acc1_3[j] + bias, 0.f));
        }
    }
    __syncthreads();

    // ---- layer 2: K=64 (2 ksteps), wave nw covers cols nw*32..+32
    f32x4 acc2[4][2];
#pragma unroll
    for (int mf = 0; mf < 4; ++mf)
#pragma unroll
        for (int nf = 0; nf < 2; ++nf)
            acc2[mf][nf] = (f32x4){0.f, 0.f, 0.f, 0.f};

#pragma unroll
    for (int ks = 0; ks < 2; ++ks) {
        int cb = ks * 4 + lk;
        s16x8 a[4], b[2];
#pragma unroll
        for (int mf = 0; mf < 4; ++mf)
            a[mf] = *(const s16x8*)&t1[(mf * 16 + l15) * 72 + cb * 8];
#pragma unroll
        for (int nf = 0; nf < 2; ++nf) {
            int n = nw * 32 + nf * 16 + l15;
            b[nf] = *(const s16x8*)&W1bT[n * 64 + ks * 32 + lk * 8];
        }
#pragma unroll
        for (int mf = 0; mf < 4; ++mf)
#pragma unroll
            for (int nf = 0; nf < 2; ++nf)
                acc2[mf][nf] = __builtin_amdgcn_mfma_f32_16x16x32_bf16(
                    a[mf], b[nf], acc2[mf][nf], 0, 0, 0);
    }
    // ---- epilogue 2: + b1b -> hb LDS
#pragma unroll
    for (int nf = 0; nf < 2; ++nf) {
        int n = nw * 32 + nf * 16 + l15;
        float bias = b1b[n];
#pragma unroll
        for (int mf = 0; mf < 4; ++mf)
#pragma unroll
            for (int j = 0; j < 4; ++j)
                hb[(mf * 16 + lk * 4 + j) * 136 + n] = f2bf(acc2[mf][nf][j] + bias);
    }
    __syncthreads();

    // ---- coalesced write-out: 4 threads x 64B per edge row
    {
        int r = tid >> 2, q = tid & 3;
        short* dst = h_csr + (size_t)(p0 + r) * 128 + q * 32;
        const short* src = &hb[r * 136 + q * 32];
#pragma unroll
        for (int j = 0; j < 4; ++j)
            *(s16x8*)&dst[j * 8] = *(const s16x8*)&src[j * 8];
    }
}

// ---------------------------------------------------------------------------
// Segmented mean: 32 nodes/block, 8 threads/node, 16 cols/thread.
// Edges of a node are contiguous rows of h_csr -> pure streaming.
// agg[n] = sum(h)/d (b1b folded per edge), 0 if d==0.
// ---------------------------------------------------------------------------
__global__ __launch_bounds__(256) void mean_kernel(
    const short* __restrict__ h_csr,
    const int* __restrict__ base, const int* __restrict__ deg,
    float* __restrict__ agg)
{
    const int tid = threadIdx.x;
    const int n = blockIdx.x * 32 + (tid >> 3);
    const int cg = tid & 7;
    const int d  = deg[n];
    const int b0 = base[n];

    v4 a0 = {0.f,0.f,0.f,0.f}, a1 = {0.f,0.f,0.f,0.f};
    v4 a2 = {0.f,0.f,0.f,0.f}, a3 = {0.f,0.f,0.f,0.f};

    for (int i = 0; i < d; ++i) {
        const short* hp = h_csr + (size_t)(b0 + i) * 128 + cg * 16;
        s16x8 u0 = *(const s16x8*)hp;
        s16x8 u1 = *(const s16x8*)&hp[8];
#pragma unroll
        for (int j = 0; j < 4; ++j) {
            a0[j] += bf2f((unsigned short)u0[j]);
            a1[j] += bf2f((unsigned short)u0[j + 4]);
            a2[j] += bf2f((unsigned short)u1[j]);
            a3[j] += bf2f((unsigned short)u1[j + 4]);
        }
    }

    float inv = (d > 0) ? 1.0f / (float)d : 0.f;
    float* dst = agg + (size_t)n * 128 + cg * 16;
    v4 o0, o1, o2, o3;
#pragma unroll
    for (int j = 0; j < 4; ++j) {
        o0[j] = a0[j] * inv; o1[j] = a1[j] * inv;
        o2[j] = a2[j] * inv; o3[j] = a3[j] * inv;
    }
    *(v4*)&dst[0]  = o0; *(v4*)&dst[4]  = o1;
    *(v4*)&dst[8]  = o2; *(v4*)&dst[12] = o3;
}

// ---------------------------------------------------------------------------
// Node MFMA kernel (unchanged, proven R5): 64 nodes/block, 8 waves.
// ---------------------------------------------------------------------------
__global__ __launch_bounds__(512, 2) void node_mfma_kernel(
    const float* __restrict__ x, const float* __restrict__ u,
    const int* __restrict__ batch,
    const float* __restrict__ agg,
    const short* __restrict__ W2aT, const short* __restrict__ W2bT,
    const float* __restrict__ b2a, const float* __restrict__ b2b,
    float* __restrict__ out)
{
    __shared__ short zb[64 * 192];
    __shared__ short tb[64 * 256];
    const int tid = threadIdx.x;
    const int node0 = blockIdx.x * 64;

#pragma unroll
    for (int it = 0; it < 4; ++it) {
        int idx = it * 512 + tid;
        int r = idx >> 5, c = idx & 31;
        int node = node0 + r;
        f32x4 v = {0.f, 0.f, 0.f, 0.f};
        if (node < NN) v = *(const f32x4*)&agg[(size_t)node * 128 + c * 4];
        s16x4 p;
        p[0] = f2bf(v[0]); p[1] = f2bf(v[1]); p[2] = f2bf(v[2]); p[3] = f2bf(v[3]);
        int ch = c >> 1;
        int sw = (ch & ~7) | ((ch ^ r) & 7);
        *(s16x4*)&zb[r * 192 + sw * 8 + (c & 1) * 4] = p;
    }
    if (tid < 64) {
        int r = tid, node = node0 + r;
        s16x8 p = {0, 0, 0, 0, 0, 0, 0, 0};
        if (node < NN) {
            p[0] = f2bf(x[node * 2]); p[1] = f2bf(x[node * 2 + 1]);
            int b = batch[node];
            p[2] = f2bf(u[b * 2]); p[3] = f2bf(u[b * 2 + 1]);
        }
        int sw = 16 | (r & 7);
        *(s16x8*)&zb[r * 192 + sw * 8] = p;
    } else if (tid < 256) {
        int t2 = tid - 64;
        int r = t2 & 63;
        int ch = 17 + (t2 >> 6);
        int sw = (ch & ~7) | ((ch ^ r) & 7);
        s16x8 zz = {0, 0, 0, 0, 0, 0, 0, 0};
        *(s16x8*)&zb[r * 192 + sw * 8] = zz;
    }
    __syncthreads();

    const int lane = tid & 63, wid = tid >> 6;
    const int l15 = lane & 15, lk = lane >> 4;
    const int nw = wid;

    f32x4 acc1[4][2];
#pragma unroll
    for (int mf = 0; mf < 4; ++mf)
#pragma unroll
        for (int nf = 0; nf < 2; ++nf)
            acc1[mf][nf] = (f32x4){0.f, 0.f, 0.f, 0.f};

#pragma unroll
    for (int ks = 0; ks < 5; ++ks) {
        s16x8 a[4], b[2];
        int cb = ks * 4 + lk;
#pragma unroll
        for (int mf = 0; mf < 4; ++mf) {
            int r = mf * 16 + l15;
            int sw = (cb & ~7) | ((cb ^ r) & 7);
            a[mf] = *(const s16x8*)&zb[r * 192 + sw * 8];
        }
#pragma unroll
        for (int nf = 0; nf < 2; ++nf) {
            int n = nw * 32 + nf * 16 + l15;
            b[nf] = *(const s16x8*)&W2aT[n * 160 + ks * 32 + lk * 8];
        }
#pragma unroll
        for (int mf = 0; mf < 4; ++mf)
#pragma unroll
            for (int nf = 0; nf < 2; ++nf)
                acc1[mf][nf] = __builtin_amdgcn_mfma_f32_16x16x32_bf16(
                    a[mf], b[nf], acc1[mf][nf], 0, 0, 0);
    }

#pragma unroll
    for (int nf = 0; nf < 2; ++nf) {
        int n = nw * 32 + nf * 16 + l15;
        float bias = b2a[n];
        int ch = n >> 3, off = n & 7;
#pragma unroll
        for (int mf = 0; mf < 4; ++mf) {
#pragma unroll
            for (int j = 0; j < 4; ++j) {
                int r = mf * 16 + lk * 4 + j;
                float vv = fmaxf(acc1[mf][nf][j] + bias, 0.f);
                int sw = (ch & ~7) | ((ch ^ r) & 7);
                tb[r * 256 + sw * 8 + off] = f2bf(vv);
            }
        }
    }
    __syncthreads();

    f32x4 acc2[4][4];
#pragma unroll
    for (int mf = 0; mf < 4; ++mf)
#pragma unroll
        for (int nf = 0; nf < 4; ++nf)
            acc2[mf][nf] = (f32x4){0.f, 0.f, 0.f, 0.f};

#pragma unroll
    for (int ks = 0; ks < 8; ++ks) {
        s16x8 a[4], b[4];
        int cb = ks * 4 + lk;
#pragma unroll
        for (int mf = 0; mf < 4; ++mf) {
            int r = mf * 16 + l15;
            int sw = (cb & ~7) | ((cb ^ r) & 7);
            a[mf] = *(const s16x8*)&tb[r * 256 + sw * 8];
        }
#pragma unroll
        for (int nf = 0; nf < 4; ++nf) {
            int n = nw * 64 + nf * 16 + l15;
            b[nf] = *(const s16x8*)&W2bT[n * 256 + ks * 32 + lk * 8];
        }
#pragma unroll
        for (int mf = 0; mf < 4; ++mf)
#pragma unroll
            for (int nf = 0; nf < 4; ++nf)
                acc2[mf][nf] = __builtin_amdgcn_mfma_f32_16x16x32_bf16(
                    a[mf], b[nf], acc2[mf][nf], 0, 0, 0);
    }

#pragma unroll
    for (int nf = 0; nf < 4; ++nf) {
        int n = nw * 64 + nf * 16 + l15;
        float bias = b2b[n];
#pragma unroll
        for (int mf = 0; mf < 4; ++mf) {
#pragma unroll
            for (int j = 0; j < 4; ++j) {
                int r = mf * 16 + lk * 4 + j;
                int node = node0 + r;
                if (node < NN)
                    out[(size_t)node * 512 + n] = acc2[mf][nf][j] + bias;
            }
        }
    }
}

extern "C" void kernel_launch(void* const* d_in, const int* in_sizes, int n_in,
                              void* d_out, int out_size, void* d_ws, size_t ws_size,
                              hipStream_t stream) {
    const float* x          = (const float*)d_in[0];
    const int*   edge_index = (const int*)d_in[1];
    const float* edge_attr  = (const float*)d_in[2];
    const float* u          = (const float*)d_in[3];
    const int*   batch      = (const int*)d_in[4];
    const float* W1a        = (const float*)d_in[5];
    const float* b1a        = (const float*)d_in[6];
    const float* W1b        = (const float*)d_in[7];
    const float* b1b        = (const float*)d_in[8];
    const float* W2a        = (const float*)d_in[9];
    const float* b2a        = (const float*)d_in[10];
    const float* W2b        = (const float*)d_in[11];
    const float* b2b        = (const float*)d_in[12];
    float* out = (float*)d_out;

    // workspace layout
    float* agg    = (float*)d_ws;                        // [NN,128] fp32
    short* W2aT   = (short*)(agg + (size_t)NN * 128);    // [256,160] bf16
    short* W2bT   = W2aT + 256 * 160;                    // [512,256] bf16
    short* W1aT   = W2bT + 512 * 256;                    // [64,32]   bf16
    short* W1bT   = W1aT + 64 * 32;                      // [128,64]  bf16
    int*   deg    = (int*)(W1bT + 128 * 64);             // [NP]
    int*   partial= deg + NP;                            // [NP]
    int*   bsum   = partial + NP;                        // [512]
    int*   boff   = bsum + 512;                          // [512]
    int*   base   = boff + 512;                          // [NP]
    int*   cursor = base + NP;                           // [NP]
    int*   csr    = cursor + NP;                         // [NE]
    int*   cidx   = csr + NE;                            // [NE]
    short* h_csr  = (short*)(cidx + NE);                 // [NE,128] bf16 (153.6MB)

    hipMemsetAsync(deg, 0, NP * sizeof(int), stream);

    prep_kernel <<<512, 256, 0, stream>>>(W2a, W2b, W1a, W1b,
                                          W2aT, W2bT, W1aT, W1bT);
    hist_kernel <<<(NE + 255) / 256, 256, 0, stream>>>(edge_index, deg);
    scan1_kernel<<<NB, 256, 0, stream>>>(deg, partial, bsum);
    scan2_kernel<<<1, 512, 0, stream>>>(bsum, boff);
    scan3_kernel<<<NB, 256, 0, stream>>>(partial, boff, base, cursor);
    fill_kernel <<<(NE + 255) / 256, 256, 0, stream>>>(edge_index, cursor, csr, cidx);

    edge_mfma_kernel<<<NE / 64, 256, 0, stream>>>(
        x, edge_attr, csr, cidx, W1aT, W1bT, b1a, b1b, h_csr);

    mean_kernel<<<NN / 32, 256, 0, stream>>>(h_csr, base, deg, agg);

    node_mfma_kernel<<<(NN + 63) / 64, 512, 0, stream>>>(
        x, u, batch, agg, W2aT, W2bT, b2a, b2b, out);
}